// Round 12
// baseline (354.129 us; speedup 1.0000x reference)
//
#include <hip/hip_runtime.h>
#include <hip/hip_bf16.h>

#define H 512
#define NLAYERS 12
#define OUTF 256
#define BMT 32      // tile rows
#define RCAP 32     // per-row record capacity
#define CAPT 512    // padded evy slots per tile (mean ~352, +10 sigma)
#define GRIDB 512   // chain blocks (2 per CU)
#define NSHARD 8

typedef unsigned short u16;
typedef unsigned int u32;
typedef u16 u16x8 __attribute__((ext_vector_type(8)));
typedef u16 u16x4 __attribute__((ext_vector_type(4)));
typedef short s16x8 __attribute__((ext_vector_type(8)));
typedef u32 u32x4 __attribute__((ext_vector_type(4)));
typedef float f32x4 __attribute__((ext_vector_type(4)));

__device__ __forceinline__ u16 f2bf(float f){
  u32 u = __float_as_uint(f);
  return (u16)((u + 0x7FFFu + ((u>>16)&1u)) >> 16);   // RTNE
}
__device__ __forceinline__ float bf_lo(u32 u){ return __uint_as_float(u << 16); }
__device__ __forceinline__ float bf_hi(u32 u){ return __uint_as_float(u & 0xffff0000u); }

// ---- k_prep: [Sx] | [Wc -> wct2 fragment-order bf16] | [edges: slots + y] --
__global__ __launch_bounds__(256) void k_prep(
    const float* __restrict__ sst, const int* __restrict__ node_idx,
    float* __restrict__ Sx,
    const float* __restrict__ Wc, u16* __restrict__ wct2,
    const int* __restrict__ arows, const int* __restrict__ acols,
    const float* __restrict__ avals,
    int* __restrict__ rcnt, float* __restrict__ y, u32* __restrict__ ebuf,
    int N, int E, int nbx0){
  __shared__ float tile[32][33];
  __shared__ float red[4];
  int b = blockIdx.x;
  int t = threadIdx.x;
  if (b < nbx0){
    int i = b*256 + t;
    float v = (i < N) ? sst[node_idx[i]] : 0.f;
    #pragma unroll
    for (int o=32;o;o>>=1) v += __shfl_xor(v,o);
    if ((t&63)==0) red[t>>6] = v;
    __syncthreads();
    if (t==0) atomicAdd(Sx, red[0]+red[1]+red[2]+red[3]);
  } else if (b < nbx0 + 256){
    int bb = b - nbx0;
    int bk = (bb & 15) * 32;    // k block
    int bh = (bb >> 4) * 32;    // h block
    int c = t & 31, r4 = t >> 5;
    #pragma unroll
    for (int p=0;p<4;p++){
      int kr = r4 + p*8;
      tile[kr][c] = Wc[(size_t)(bk+kr)*H + bh + c];
    }
    __syncthreads();
    int c2 = t & 31, kg = t >> 5;
    int h = bh + c2;
    int base = (((h>>6)*16 + (bk>>5))*4 + ((h>>4)&3))*512 + (h&15)*32;
    u16x4 o;
    #pragma unroll
    for (int i=0;i<4;i++) o[i] = f2bf(tile[kg*4+i][c2]);
    *(u16x4*)(wct2 + base + kg*4) = o;
  } else {
    int e = (b - nbx0 - 256)*256 + t;
    if (e < E){
      int r = arows[e], c = acols[e];
      float v = avals[e];
      float x0c = sst[node_idx[c]];
      int pos = atomicAdd(&rcnt[r], 1);
      if (pos < RCAP)
        ebuf[(size_t)r*RCAP + pos] = (u32)c | ((u32)f2bf(v) << 16);
      atomicAdd(&y[r], v * x0c);
    }
  }
}

// ---- FUSED pipelined chain: per region {stage-issue(i+2) | GEMM(i) ∥ z(i+1)
//      interleaved | epi(i) | stage-finish(i+2)} with ONE barrier per tile.
// z[r,h] = y[r] + 0.505*(w_h*A_r + b_h*B_r) + 0.495*sum_e v_e*|y_ce*w_h+b_h|
// zbuf layout: byte(r,h) = r*1024 + (2h ^ ((r&7)<<4)); evy packed bf16(v|y_c).
__global__ __launch_bounds__(512, 4) void k_fused(
    const int* __restrict__ rcnt, const u32* __restrict__ ebuf,
    const float* __restrict__ y,
    const float* __restrict__ W1, const float* __restrict__ b1,
    const u16* __restrict__ wct2, const float* __restrict__ bc,
    float* __restrict__ pooled_acc, int N, int ntiles)
{
  __shared__ __align__(16) unsigned char zbuf[2][BMT*1024];  // 2 x 32KB
  __shared__ __align__(16) u32 evy2[2][CAPT];                // 2 x 2KB
  __shared__ int   meta_rs[3][BMT+1];
  __shared__ float meta_y[3][BMT];

  int t = threadIdx.x, lane = t & 63, wid = t >> 6, bid = blockIdx.x;
  int r15 = lane & 15, rg = lane >> 4;
  int swz = (r15 & 7) << 4;

  float w1v[8], b1v[8];
  *(float4*)&w1v[0] = *(const float4*)(W1 + lane*8);
  *(float4*)&w1v[4] = *(const float4*)(W1 + lane*8 + 4);
  *(float4*)&b1v[0] = *(const float4*)(b1 + lane*8);
  *(float4*)&b1v[4] = *(const float4*)(b1 + lane*8 + 4);

  // ---- stage: issue loads (records + counts + y) --------------------------
  auto stage_load = [&](int tile_, u32* recs, int& c_, float& yv){
    int m0 = tile_ * BMT;
    c_ = 0; yv = 0.f;
    if (lane < BMT){
      int gr = m0 + lane;
      if (gr < N){ c_ = min(rcnt[gr], RCAP); yv = y[gr]; }
    }
    const u32* ebr = ebuf + (size_t)m0 * RCAP;
    #pragma unroll
    for (int i = 0; i < 2; ++i){
      int j = t + i*512;
      recs[i] = (m0 + (j >> 5) < N) ? ebr[j] : 0u;
    }
  };
  // ---- stage: scan (in-register) + meta + y-gather + evy scatter ----------
  auto stage_finish = [&](int sel, int msel, const u32* recs, int c_, float yv){
    int pad = (c_ + 3) & ~3;
    int incl = pad;
    #pragma unroll
    for (int off = 1; off < 32; off <<= 1){
      int u = __shfl_up(incl, off);
      if (lane >= off) incl += u;
    }
    int excl = incl - pad;
    if (wid == 0 && lane < BMT){
      meta_rs[msel][lane+1] = min(incl, CAPT);
      meta_y[msel][lane] = yv;
      if (lane == 0) meta_rs[msel][0] = 0;
    }
    #pragma unroll
    for (int i = 0; i < 2; ++i){
      int j = t + i*512;
      int row = j >> 5, idx = j & 31;
      int cR  = __shfl(c_,  row);
      int pdR = __shfl(pad, row);
      int exR = __shfl(excl, row);
      if (idx < pdR){
        u32 val = 0u;
        if (idx < cR){
          u32 rec = recs[i];
          float yc = y[rec & 0xffffu];
          val = (rec & 0xffff0000u) | (u32)f2bf(yc);
        }
        int pos = exR + idx;
        if (pos < CAPT) evy2[sel][pos] = val;
      }
    }
  };
  // ---- z: one dual-row pair (rows wid*4 + 2pr, +1) ------------------------
  auto zpair = [&](int msel, int sel, int pr){
    int r0 = wid*4 + 2*pr, r1 = r0 + 1;
    int jb0 = meta_rs[msel][r0], je0 = meta_rs[msel][r0+1];
    int jb1 = meta_rs[msel][r1], je1 = meta_rs[msel][r1+1];
    int n0 = (je0 - jb0) >> 2, n1 = (je1 - jb1) >> 2;
    int nb = max(n0, n1);
    float a0[8] = {0,0,0,0,0,0,0,0}, a1[8] = {0,0,0,0,0,0,0,0};
    float A0 = 0.f, B0 = 0.f, A1 = 0.f, B1 = 0.f;
    const u32* ev = evy2[sel];
    u32x4 p0 = *(const u32x4*)&ev[min(jb0, CAPT-4)];
    u32x4 p1 = *(const u32x4*)&ev[min(jb1, CAPT-4)];
    for (int b = 0; b < nb; ++b){
      int j0 = jb0 + ((b+1 < n0) ? (b+1)*4 : 0);
      int j1 = jb1 + ((b+1 < n1) ? (b+1)*4 : 0);
      u32x4 q0 = *(const u32x4*)&ev[min(j0, CAPT-4)];
      u32x4 q1 = *(const u32x4*)&ev[min(j1, CAPT-4)];
      if (b < n0){
        #pragma unroll
        for (int i = 0; i < 4; ++i){
          float v = bf_hi(p0[i]), yc = bf_lo(p0[i]);
          A0 = fmaf(v, yc, A0); B0 += v;
          #pragma unroll
          for (int k = 0; k < 8; ++k){
            float s = fmaf(yc, w1v[k], b1v[k]);
            a0[k] = fmaf(v, fabsf(s), a0[k]);
          }
        }
      }
      if (b < n1){
        #pragma unroll
        for (int i = 0; i < 4; ++i){
          float v = bf_hi(p1[i]), yc = bf_lo(p1[i]);
          A1 = fmaf(v, yc, A1); B1 += v;
          #pragma unroll
          for (int k = 0; k < 8; ++k){
            float s = fmaf(yc, w1v[k], b1v[k]);
            a1[k] = fmaf(v, fabsf(s), a1[k]);
          }
        }
      }
      p0 = q0; p1 = q1;
    }
    float yr0 = meta_y[msel][r0], yr1 = meta_y[msel][r1];
    float A05 = 0.505f*A0, B05 = 0.505f*B0;
    float A15 = 0.505f*A1, B15 = 0.505f*B1;
    u16x8 o0, o1;
    #pragma unroll
    for (int k = 0; k < 8; ++k){
      o0[k] = f2bf(fmaf(0.495f, a0[k], fmaf(w1v[k], A05, fmaf(b1v[k], B05, yr0))));
      o1[k] = f2bf(fmaf(0.495f, a1[k], fmaf(w1v[k], A15, fmaf(b1v[k], B15, yr1))));
    }
    unsigned char* zb = zbuf[sel];
    *(u16x8*)(zb + r0*1024 + ((lane*16) ^ ((r0 & 7) << 4))) = o0;
    *(u16x8*)(zb + r1*1024 + ((lane*16) ^ ((r1 & 7) << 4))) = o1;
  };

  // ---- prologue: stage(t0); B; z(t0)+stage(t1); B  (every block has >=2)
  {
    u32 rec0[2]; int c0; float yv0;
    stage_load(bid, rec0, c0, yv0);
    stage_finish(0, 0, rec0, c0, yv0);
  }
  __syncthreads();
  {
    zpair(0, 0, 0); zpair(0, 0, 1);
    u32 rec1[2]; int c1; float yv1;
    stage_load(bid + GRIDB, rec1, c1, yv1);
    stage_finish(1, 1, rec1, c1, yv1);
  }
  __syncthreads();

  const u16* bbase = wct2 + (size_t)wid*32768 + r15*32 + rg*8;
  int shard = (bid & (NSHARD-1)) << 9;

  for (int k = 0; ; ++k){
    int tk = bid + k*GRIDB;
    int zsel = k & 1, msel = k % 3;
    bool zv = (tk + GRIDB)   < ntiles;
    bool sv = (tk + 2*GRIDB) < ntiles;
    int mz = (k+1) % 3, ms = (k+2) % 3;

    u32 recs[2]; int cS = 0; float yS = 0.f;
    if (sv) stage_load(tk + 2*GRIDB, recs, cS, yS);

    // ---- GEMM(tk) interleaved with z(tk+1): alternate MFMA / VALU bursts
    f32x4 acc[2][4] = {};
    const unsigned char* zb = zbuf[zsel];
    #pragma unroll
    for (int g = 0; g < 2; ++g){
      #pragma unroll
      for (int kt = g*8; kt < g*8 + 8; ++kt){
        s16x8 af[2], bf[4];
        #pragma unroll
        for (int n = 0; n < 4; ++n)
          bf[n] = *(const s16x8*)(bbase + ((kt*4 + n) << 9));
        #pragma unroll
        for (int m = 0; m < 2; ++m)
          af[m] = *(const s16x8*)(zb + (m*16 + r15)*1024 + ((kt*64 + rg*16) ^ swz));
        #pragma unroll
        for (int m = 0; m < 2; ++m)
          #pragma unroll
          for (int n = 0; n < 4; ++n)
            acc[m][n] = __builtin_amdgcn_mfma_f32_16x16x32_bf16(af[m], bf[n], acc[m][n], 0,0,0);
      }
      if (zv) zpair(mz, zsel ^ 1, g);
    }

    // ---- epilogue(tk): leaky(acc+bc) colsum + x1-pool, sharded atomics
    {
      int rv = min(BMT, N - tk*BMT);
      float yrow[16];
      #pragma unroll
      for (int i = 0; i < 16; ++i)
        yrow[i] = meta_y[msel][min(rg*16 + i, BMT-1)];
      int nvalid = rv - rg*16;
      #pragma unroll
      for (int n = 0; n < 4; ++n){
        int gc = wid*64 + n*16 + r15;
        float bcv = bc[gc], w1c = W1[gc], b1c = b1[gc];
        float cs = 0.f;
        #pragma unroll
        for (int m = 0; m < 2; ++m){
          int rr0 = m*16 + rg*4;
          #pragma unroll
          for (int j = 0; j < 4; ++j){
            if (rr0 + j < rv){
              float wv2 = acc[m][n][j] + bcv;
              cs += fmaxf(wv2, 0.01f*wv2);
            }
          }
        }
        #pragma unroll
        for (int i = 0; i < 16; ++i){
          if (i < nvalid){
            float v = fmaf(yrow[i], w1c, b1c);
            cs += fmaxf(v, 0.01f*v);
          }
        }
        cs += __shfl_xor(cs, 16);
        cs += __shfl_xor(cs, 32);
        if (rg == 0) atomicAdd(&pooled_acc[shard + gc], cs);
      }
    }

    if (sv) stage_finish(zsel, ms, recs, cS, yS);
    if (!zv) break;
    __syncthreads();
  }
}

// ------- gamma/beta heads (sums shards, finalizes pooled): 1 wave / row --
__global__ __launch_bounds__(256) void k_heads(const float* __restrict__ pooled_acc,
        const float* __restrict__ Sx,
        const float* __restrict__ Wg, const float* __restrict__ bg,
        const float* __restrict__ Wb, const float* __restrict__ bb,
        float* __restrict__ out, float invN){
  __shared__ float sp[H];
  int t = threadIdx.x;
  float sx = Sx[0];
  float s0 = 0.f, s1 = 0.f;
  #pragma unroll
  for (int s = 0; s < NSHARD; ++s){
    s0 += pooled_acc[s*512 + t];
    s1 += pooled_acc[s*512 + t + 256];
  }
  sp[t]     = (s0 + sx) * invN;
  sp[t+256] = (s1 + sx) * invN;
  __syncthreads();
  int wid = t >> 6, l = t & 63;
  int o = blockIdx.x*4 + wid;
  int head = o / (NLAYERS*OUTF);
  int rem  = o - head*(NLAYERS*OUTF);
  const float* W = (head ? Wb : Wg) + (size_t)rem * H;
  float4 wa = *(const float4*)(W + l*8);
  float4 wb = *(const float4*)(W + l*8 + 4);
  float4 pa = *(const float4*)(sp + l*8);
  float4 pb = *(const float4*)(sp + l*8 + 4);
  float acc = wa.x*pa.x + wa.y*pa.y + wa.z*pa.z + wa.w*pa.w
            + wb.x*pb.x + wb.y*pb.y + wb.z*pb.z + wb.w*pb.w;
  #pragma unroll
  for (int off=32; off; off>>=1) acc += __shfl_xor(acc, off);
  if (l == 0) out[o] = acc + (head ? bb : bg)[rem];
}

extern "C" void kernel_launch(void* const* d_in, const int* in_sizes, int n_in,
                              void* d_out, int out_size, void* d_ws, size_t ws_size,
                              hipStream_t stream){
  const float* sst      = (const float*)d_in[0];
  const int*   node_idx = (const int*)d_in[1];
  const int*   arows    = (const int*)d_in[2];
  const int*   acols    = (const int*)d_in[3];
  const float* avals    = (const float*)d_in[4];
  const float* W1       = (const float*)d_in[5];
  const float* b1       = (const float*)d_in[6];
  const float* Wc       = (const float*)d_in[7];
  const float* bc       = (const float*)d_in[8];
  const float* Wg       = (const float*)d_in[9];
  const float* bg       = (const float*)d_in[10];
  const float* Wb       = (const float*)d_in[11];
  const float* bb       = (const float*)d_in[12];

  const int N = in_sizes[1];
  const int E = in_sizes[2];
  const int ntiles = (N + BMT - 1) / BMT;

  char* w = (char*)d_ws;
  size_t off = 0;
  auto take = [&](size_t b)->char*{ char* p = w + off; off += (b + 255) & ~(size_t)255; return p; };

  size_t zero_words = (size_t)2*N + NSHARD*512 + 1;  // y | rcnt | pooled[8] | Sx
  float* y          = (float*)take(zero_words*4);
  int*   rcnt       = (int*)(y + N);
  float* pooled_acc = (float*)(rcnt + N);
  float* Sx         = pooled_acc + NSHARD*512;
  u32*   ebuf       = (u32*)take((size_t)N*RCAP*4);
  u16*   wct2       = (u16*)take((size_t)H*H*2);

  hipMemsetAsync(y, 0, zero_words*4, stream);

  int nbx0 = (N + 255)/256;
  int nbE = (E + 255)/256;
  k_prep <<<nbx0 + 256 + nbE, 256, 0, stream>>>(sst, node_idx, Sx, Wc, wct2,
                                                arows, acols, avals,
                                                rcnt, y, ebuf, N, E, nbx0);
  k_fused<<<GRIDB, 512, 0, stream>>>(rcnt, ebuf, y, W1, b1, wct2, bc,
                                     pooled_acc, N, ntiles);
  k_heads<<<(2*NLAYERS*OUTF)/4, 256, 0, stream>>>(pooled_acc, Sx, Wg, bg, Wb, bb,
                                                  (float*)d_out, 1.0f/(float)N);
}

// Round 13
// 108.426 us; speedup vs baseline: 3.2661x; 3.2661x over previous
//
#include <hip/hip_runtime.h>
#include <hip/hip_bf16.h>

#define H 512
#define NLAYERS 12
#define OUTF 256
#define BM 64
#define RCAP 32     // per-row record capacity (Poisson(8): P(>32) ~ 1e-12)
#define CAPL 960    // padded slots per block: ne<=704 (+8.5 sigma) + 64*3 pad
#define NSHARD 8

typedef unsigned short u16;
typedef unsigned int u32;
typedef u16 u16x8 __attribute__((ext_vector_type(8)));
typedef u16 u16x4 __attribute__((ext_vector_type(4)));
typedef short s16x8 __attribute__((ext_vector_type(8)));
typedef u32 u32x4 __attribute__((ext_vector_type(4)));
typedef float f32x4 __attribute__((ext_vector_type(4)));

__device__ __forceinline__ u16 f2bf(float f){
  u32 u = __float_as_uint(f);
  return (u16)((u + 0x7FFFu + ((u>>16)&1u)) >> 16);   // RTNE
}
__device__ __forceinline__ float bf_lo(u32 u){ return __uint_as_float(u << 16); }
__device__ __forceinline__ float bf_hi(u32 u){ return __uint_as_float(u & 0xffff0000u); }

// ---- k_prep: [Sx] | [Wc -> wct2 fragment-order bf16] | [edges: slots + y] --
// wct2 element (h,k) at: (((h>>6)*16 + (k>>5))*4 + ((h>>4)&3))*512
//                        + (h&15)*32 + ((k>>3)&3)*8 + (k&7)
__global__ __launch_bounds__(256) void k_prep(
    const float* __restrict__ sst, const int* __restrict__ node_idx,
    float* __restrict__ Sx,
    const float* __restrict__ Wc, u16* __restrict__ wct2,
    const int* __restrict__ arows, const int* __restrict__ acols,
    const float* __restrict__ avals,
    int* __restrict__ rcnt, float* __restrict__ y, u32* __restrict__ ebuf,
    int N, int E, int nbx0){
  __shared__ float tile[32][33];
  __shared__ float red[4];
  int b = blockIdx.x;
  int t = threadIdx.x;
  if (b < nbx0){
    int i = b*256 + t;
    float v = (i < N) ? sst[node_idx[i]] : 0.f;
    #pragma unroll
    for (int o=32;o;o>>=1) v += __shfl_xor(v,o);
    if ((t&63)==0) red[t>>6] = v;
    __syncthreads();
    if (t==0) atomicAdd(Sx, red[0]+red[1]+red[2]+red[3]);
  } else if (b < nbx0 + 256){
    int bb = b - nbx0;
    int bk = (bb & 15) * 32;    // k block (=kt*32)
    int bh = (bb >> 4) * 32;    // h block
    int c = t & 31, r4 = t >> 5;
    #pragma unroll
    for (int p=0;p<4;p++){
      int kr = r4 + p*8;
      tile[kr][c] = Wc[(size_t)(bk+kr)*H + bh + c];
    }
    __syncthreads();
    int c2 = t & 31, kg = t >> 5;
    int h = bh + c2;
    int base = (((h>>6)*16 + (bk>>5))*4 + ((h>>4)&3))*512 + (h&15)*32;
    u16x4 o;
    #pragma unroll
    for (int i=0;i<4;i++) o[i] = f2bf(tile[kg*4+i][c2]);
    *(u16x4*)(wct2 + base + kg*4) = o;
  } else {
    int e = (b - nbx0 - 256)*256 + t;
    if (e < E){
      int r = arows[e], c = acols[e];
      float v = avals[e];
      float x0c = sst[node_idx[c]];            // recompute gather (L2-resident)
      int pos = atomicAdd(&rcnt[r], 1);        // ~8 hits per address
      if (pos < RCAP)
        ebuf[(size_t)r*RCAP + pos] = (u32)c | ((u32)f2bf(v) << 16);
      atomicAdd(&y[r], v * x0c);
    }
  }
}

// ---- FUSED: stage rows -> z build in LDS + MFMA GEMM + pooled epilogue --
// z[r,h] = y[r] + 0.505*(w_h*A_r + b_h*B_r) + 0.495*sum_e v_e*|y_ce*w_h+b_h|
// evy: packed (bf16 v | bf16 y_c), rows padded to x4 (b128 uniform batches).
// zlds layout: byte(r,h) = r*1024 + (2h ^ ((r&7)<<4))  [conflict-free r/w]
// z-phase: dual-row interleaved streams (2 independent LDS load chains).
// GEMM: 8 waves, wave w = 64 rows x cols [w*64,+64); B from L2 via explicit
//   1-deep double-buffer; setprio(1). Epilogue atomics SHARDED x8 by block.
__global__ __launch_bounds__(512, 4) void k_fused(
    const int* __restrict__ rcnt, const u32* __restrict__ ebuf,
    const float* __restrict__ y,
    const float* __restrict__ W1, const float* __restrict__ b1,
    const u16* __restrict__ wct2, const float* __restrict__ bc,
    float* __restrict__ pooled_acc, int N)
{
  __shared__ __align__(16) unsigned char zlds[BM*1024];  // 64KB swizzled bf16 z
  __shared__ __align__(16) u32 evy[CAPL];                // packed (v, y_c)
  __shared__ int rs[BM+1];
  __shared__ int cnt_s[BM];
  __shared__ float y_r[BM];

  int t = threadIdx.x;
  int lane = t & 63, wid = t >> 6;
  int m0 = blockIdx.x * BM;
  int rows_valid = min(BM, N - m0);

  // wave 0: per-row counts + padded exclusive scan, fully in-wave
  if (wid == 0){
    int c_ = (lane < rows_valid) ? min(rcnt[m0 + lane], RCAP) : 0;
    int incl = (c_ + 3) & ~3;
    #pragma unroll
    for (int off = 1; off < 64; off <<= 1){
      int u = __shfl_up(incl, off);
      if (lane >= off) incl += u;
    }
    cnt_s[lane] = c_;
    rs[lane+1] = min(incl, CAPL);
    if (lane == 0) rs[0] = 0;
  }
  if (t < BM) y_r[t] = (t < rows_valid) ? y[m0 + t] : 0.f;
  for (int j = t; j < CAPL; j += 512) evy[j] = 0u;
  __syncthreads();

  // scatter: 4-wide register prefetch (records, then gathers, then writes)
  {
    const u32* ebr = ebuf + (size_t)m0 * RCAP;
    u32 rec[4];
    #pragma unroll
    for (int i = 0; i < 4; ++i) rec[i] = ebr[t + i*512];
    float yc[4];
    #pragma unroll
    for (int i = 0; i < 4; ++i){
      int c = (int)(rec[i] & 0xffffu);
      yc[i] = y[min(c, N-1)];                  // speculative-safe gather
    }
    #pragma unroll
    for (int i = 0; i < 4; ++i){
      int j = t + i*512;
      int row = j >> 5, idx = j & (RCAP-1);
      if (idx < cnt_s[row]){
        int pos = rs[row] + idx;
        if (pos < CAPL)
          evy[pos] = (rec[i] & 0xffff0000u) | (u32)f2bf(yc[i]);
      }
    }
  }
  __syncthreads();

  // ---- z phase: 8 rows/wave as 4 dual-row interleaved streams
  {
    float w1v[8], b1v[8];
    *(float4*)&w1v[0] = *(const float4*)(W1 + lane*8);
    *(float4*)&w1v[4] = *(const float4*)(W1 + lane*8 + 4);
    *(float4*)&b1v[0] = *(const float4*)(b1 + lane*8);
    *(float4*)&b1v[4] = *(const float4*)(b1 + lane*8 + 4);
    #pragma unroll
    for (int r8 = 0; r8 < 8; r8 += 2){
      int r0 = wid*8 + r8, r1 = r0 + 1;
      int jb0 = rs[r0], je0 = rs[r0+1];
      int jb1 = rs[r1], je1 = rs[r1+1];
      int n0 = (je0 - jb0) >> 2, n1 = (je1 - jb1) >> 2;
      int nb = max(n0, n1);
      float a0[8] = {0,0,0,0,0,0,0,0}, a1[8] = {0,0,0,0,0,0,0,0};
      float A0 = 0.f, B0 = 0.f, A1 = 0.f, B1 = 0.f;
      u32x4 p0 = *(const u32x4*)&evy[jb0];
      u32x4 p1 = *(const u32x4*)&evy[jb1];
      for (int b = 0; b < nb; ++b){
        int j0 = jb0 + ((b+1 < n0) ? (b+1)*4 : 0);   // wave-uniform clamp
        int j1 = jb1 + ((b+1 < n1) ? (b+1)*4 : 0);
        u32x4 q0 = *(const u32x4*)&evy[j0];
        u32x4 q1 = *(const u32x4*)&evy[j1];
        if (b < n0){
          #pragma unroll
          for (int i = 0; i < 4; ++i){
            float v = bf_hi(p0[i]), yc = bf_lo(p0[i]);
            A0 = fmaf(v, yc, A0); B0 += v;
            #pragma unroll
            for (int k = 0; k < 8; ++k){
              float s = fmaf(yc, w1v[k], b1v[k]);
              a0[k] = fmaf(v, fabsf(s), a0[k]);
            }
          }
        }
        if (b < n1){
          #pragma unroll
          for (int i = 0; i < 4; ++i){
            float v = bf_hi(p1[i]), yc = bf_lo(p1[i]);
            A1 = fmaf(v, yc, A1); B1 += v;
            #pragma unroll
            for (int k = 0; k < 8; ++k){
              float s = fmaf(yc, w1v[k], b1v[k]);
              a1[k] = fmaf(v, fabsf(s), a1[k]);
            }
          }
        }
        p0 = q0; p1 = q1;
      }
      float yr0 = y_r[r0], yr1 = y_r[r1];
      float A05 = 0.505f*A0, B05 = 0.505f*B0;
      float A15 = 0.505f*A1, B15 = 0.505f*B1;
      u16x8 o0, o1;
      #pragma unroll
      for (int k = 0; k < 8; ++k){
        o0[k] = f2bf(fmaf(0.495f, a0[k], fmaf(w1v[k], A05, fmaf(b1v[k], B05, yr0))));
        o1[k] = f2bf(fmaf(0.495f, a1[k], fmaf(w1v[k], A15, fmaf(b1v[k], B15, yr1))));
      }
      *(u16x8*)(zlds + r0*1024 + ((lane*16) ^ ((r0 & 7) << 4))) = o0;
      *(u16x8*)(zlds + r1*1024 + ((lane*16) ^ ((r1 & 7) << 4))) = o1;
    }
  }
  __syncthreads();

  // ---- GEMM phase: NO barriers; A LDS-resident, B via 1-deep dbuf
  int r15 = lane & 15, rg = lane >> 4;
  int nc = wid * 64;
  int swz = (r15 & 7) << 4;
  f32x4 acc4[4][4] = {};
  const u16* bbase = wct2 + (size_t)wid*32768 + r15*32 + rg*8;

  s16x8 bcur[4];
  #pragma unroll
  for (int n = 0; n < 4; ++n)
    bcur[n] = *(const s16x8*)(bbase + (n << 9));

  __builtin_amdgcn_s_setprio(1);
  #pragma unroll
  for (int kt = 0; kt < 16; ++kt){
    s16x8 bnxt[4];
    if (kt < 15){
      #pragma unroll
      for (int n = 0; n < 4; ++n)
        bnxt[n] = *(const s16x8*)(bbase + (((kt+1)*4 + n) << 9));
    }
    s16x8 af[4];
    #pragma unroll
    for (int m = 0; m < 4; ++m){
      int off = (m*16 + r15)*1024 + ((kt*64 + rg*16) ^ swz);
      af[m] = *(const s16x8*)(zlds + off);
    }
    #pragma unroll
    for (int m = 0; m < 4; ++m)
      #pragma unroll
      for (int n = 0; n < 4; ++n)
        acc4[m][n] = __builtin_amdgcn_mfma_f32_16x16x32_bf16(af[m], bcur[n], acc4[m][n], 0,0,0);
    if (kt < 15){
      #pragma unroll
      for (int n = 0; n < 4; ++n) bcur[n] = bnxt[n];
    }
  }
  __builtin_amdgcn_s_setprio(0);

  // ---- epilogue: leaky(acc+bc) colsum + x1-pool, SHARDED atomics
  float yrow[16];
  #pragma unroll
  for (int i = 0; i < 16; ++i) yrow[i] = y_r[rg*16 + i];
  int nvalid = rows_valid - rg*16;
  int shard = (blockIdx.x & (NSHARD-1)) << 9;

  #pragma unroll
  for (int n = 0; n < 4; ++n){
    int gc = nc + n*16 + r15;
    float bcv = bc[gc], w1c = W1[gc], b1c = b1[gc];
    float cs = 0.f;
    #pragma unroll
    for (int m = 0; m < 4; ++m){
      int r0 = m*16 + rg*4;
      #pragma unroll
      for (int j = 0; j < 4; ++j){
        if (r0 + j < rows_valid){
          float wv2 = acc4[m][n][j] + bcv;
          cs += fmaxf(wv2, 0.01f*wv2);
        }
      }
    }
    #pragma unroll
    for (int i = 0; i < 16; ++i){
      if (i < nvalid){
        float v = fmaf(yrow[i], w1c, b1c);
        cs += fmaxf(v, 0.01f*v);
      }
    }
    cs += __shfl_xor(cs, 16);
    cs += __shfl_xor(cs, 32);
    if (rg == 0) atomicAdd(&pooled_acc[shard + gc], cs);
  }
}

// --- gamma/beta heads (sums shards, finalizes pooled): 1 wave / row -----
__global__ __launch_bounds__(256) void k_heads(const float* __restrict__ pooled_acc,
        const float* __restrict__ Sx,
        const float* __restrict__ Wg, const float* __restrict__ bg,
        const float* __restrict__ Wb, const float* __restrict__ bb,
        float* __restrict__ out, float invN){
  __shared__ float sp[H];
  int t = threadIdx.x;
  float sx = Sx[0];
  float s0 = 0.f, s1 = 0.f;
  #pragma unroll
  for (int s = 0; s < NSHARD; ++s){
    s0 += pooled_acc[s*512 + t];
    s1 += pooled_acc[s*512 + t + 256];
  }
  sp[t]     = (s0 + sx) * invN;
  sp[t+256] = (s1 + sx) * invN;
  __syncthreads();
  int wid = t >> 6, l = t & 63;
  int o = blockIdx.x*4 + wid;           // 0..6143
  int head = o / (NLAYERS*OUTF);        // 0=gamma 1=beta
  int rem  = o - head*(NLAYERS*OUTF);
  const float* W = (head ? Wb : Wg) + (size_t)rem * H;
  float4 wa = *(const float4*)(W + l*8);
  float4 wb = *(const float4*)(W + l*8 + 4);
  float4 pa = *(const float4*)(sp + l*8);
  float4 pb = *(const float4*)(sp + l*8 + 4);
  float acc = wa.x*pa.x + wa.y*pa.y + wa.z*pa.z + wa.w*pa.w
            + wb.x*pb.x + wb.y*pb.y + wb.z*pb.z + wb.w*pb.w;
  #pragma unroll
  for (int off=32; off; off>>=1) acc += __shfl_xor(acc, off);
  if (l == 0) out[o] = acc + (head ? bb : bg)[rem];
}

extern "C" void kernel_launch(void* const* d_in, const int* in_sizes, int n_in,
                              void* d_out, int out_size, void* d_ws, size_t ws_size,
                              hipStream_t stream){
  const float* sst      = (const float*)d_in[0];
  const int*   node_idx = (const int*)d_in[1];
  const int*   arows    = (const int*)d_in[2];
  const int*   acols    = (const int*)d_in[3];
  const float* avals    = (const float*)d_in[4];
  const float* W1       = (const float*)d_in[5];
  const float* b1       = (const float*)d_in[6];
  const float* Wc       = (const float*)d_in[7];
  const float* bc       = (const float*)d_in[8];
  const float* Wg       = (const float*)d_in[9];
  const float* bg       = (const float*)d_in[10];
  const float* Wb       = (const float*)d_in[11];
  const float* bb       = (const float*)d_in[12];

  const int N = in_sizes[1];
  const int E = in_sizes[2];
  const int nblk = (N + BM - 1) / BM;

  char* w = (char*)d_ws;
  size_t off = 0;
  auto take = [&](size_t b)->char*{ char* p = w + off; off += (b + 255) & ~(size_t)255; return p; };

  size_t zero_words = (size_t)2*N + NSHARD*512 + 1;  // y | rcnt | pooled[8] | Sx
  float* y          = (float*)take(zero_words*4);
  int*   rcnt       = (int*)(y + N);
  float* pooled_acc = (float*)(rcnt + N);
  float* Sx         = pooled_acc + NSHARD*512;
  u32*   ebuf       = (u32*)take((size_t)N*RCAP*4);
  u16*   wct2       = (u16*)take((size_t)H*H*2);

  hipMemsetAsync(y, 0, zero_words*4, stream);

  int nbx0 = (N + 255)/256;
  int nbE = (E + 255)/256;
  k_prep <<<nbx0 + 256 + nbE, 256, 0, stream>>>(sst, node_idx, Sx, Wc, wct2,
                                                arows, acols, avals,
                                                rcnt, y, ebuf, N, E, nbx0);
  k_fused<<<nblk, 512, 0, stream>>>(rcnt, ebuf, y, W1, b1, wct2, bc, pooled_acc, N);
  k_heads<<<(2*NLAYERS*OUTF)/4, 256, 0, stream>>>(pooled_acc, Sx, Wg, bg, Wb, bb,
                                                  (float*)d_out, 1.0f/(float)N);
}